// Round 3
// baseline (1343.886 us; speedup 1.0000x reference)
//
#include <hip/hip_runtime.h>
#include <hip/hip_bf16.h>

// ---------------------------------------------------------------------------
// ResidualBlock: GMMConv(x)->BN->ELU->GMMConv->BN  +  GMMConv_sc(x)->BN ; ELU
// N=50000, E=800000, C=64, K_main=5, K_sc=1. fp32.
// Round 3: edge-parallel precompute of gaussian weights (kills per-edge exp
// in the node-wave agg loop); agg loop = gather + 6 FMA; fused dual GEMM for
// layer1 + shortcut; BN stats fused into GEMM epilogues.
// ---------------------------------------------------------------------------

#define EPS_SIGMA 1e-15f
#define BN_EPS    1e-5f

// --- dtype detect: int64 edge_index has all-zero high words -----------------
__global__ void detect_kernel(const void* ei, int* flag) {
  const int* p = (const int*)ei;
  int allzero = 1;
  for (int i = 1; i < 512; i += 2) {
    if (p[i] != 0) { allzero = 0; break; }
  }
  *flag = allzero;  // 1 => int64 layout, 0 => int32 layout
}

__device__ __forceinline__ int load_idx(const void* ei, size_t pos, int is64) {
  if (is64) return (int)((const long long*)ei)[pos];
  return ((const int*)ei)[pos];
}

// --- CSR build ---------------------------------------------------------------
__global__ void hist_kernel(const void* ei, int E, const int* flag, int* cnt) {
  int e = blockIdx.x * blockDim.x + threadIdx.x;
  if (e >= E) return;
  int d = load_idx(ei, (size_t)E + e, *flag);
  atomicAdd(&cnt[d], 1);
}

__global__ __launch_bounds__(256) void scan1(const int* __restrict__ cnt,
                                             int* __restrict__ row_ptr,
                                             int* __restrict__ partials, int n) {
  int tid = threadIdx.x;
  int base = blockIdx.x * 2048 + tid * 8;
  int v[8], pre[8];
  int run = 0;
#pragma unroll
  for (int j = 0; j < 8; ++j) {
    int idx = base + j;
    v[j] = (idx < n) ? cnt[idx] : 0;
    pre[j] = run;
    run += v[j];
  }
  __shared__ int sd[256];
  sd[tid] = run;
  __syncthreads();
  for (int off = 1; off < 256; off <<= 1) {
    int t = (tid >= off) ? sd[tid - off] : 0;
    __syncthreads();
    sd[tid] += t;
    __syncthreads();
  }
  int excl = sd[tid] - run;
#pragma unroll
  for (int j = 0; j < 8; ++j) {
    int idx = base + j;
    if (idx < n) row_ptr[idx] = excl + pre[j];
  }
  if (tid == 255) partials[blockIdx.x] = sd[255];
}

__global__ void scan2(int* partials, int nb, int* row_ptr, int n) {
  __shared__ int sd[256];
  int tid = threadIdx.x;
  int v = (tid < nb) ? partials[tid] : 0;
  sd[tid] = v;
  __syncthreads();
  for (int off = 1; off < 256; off <<= 1) {
    int t = (tid >= off) ? sd[tid - off] : 0;
    __syncthreads();
    sd[tid] += t;
    __syncthreads();
  }
  if (tid < nb) partials[tid] = sd[tid] - v;
  if (tid == nb - 1) row_ptr[n] = sd[tid];
}

__global__ void scan3(int* __restrict__ row_ptr, const int* __restrict__ partials,
                      int* __restrict__ cnt, int n) {
  int i = blockIdx.x * 256 + threadIdx.x;
  if (i < n) {
    row_ptr[i] += partials[i >> 11];
    cnt[i] = 0;
  }
}

__global__ void scatter_kernel(const void* ei, const float* __restrict__ ea, int E,
                               const int* flag, const int* __restrict__ row_ptr,
                               int* cursor, int* __restrict__ csr_src,
                               float* __restrict__ csr_ea) {
  int e = blockIdx.x * blockDim.x + threadIdx.x;
  if (e >= E) return;
  int is64 = *flag;
  int s = load_idx(ei, (size_t)e, is64);
  int d = load_idx(ei, (size_t)E + e, is64);
  int pos = atomicAdd(&cursor[d], 1);
  int slot = row_ptr[d] + pos;
  csr_src[slot] = s;
  csr_ea[slot] = ea[e];
}

// --- edge-parallel gaussian weights: wbuf[e][0..KT-1], AoS padded to 8 ------
template <int KA, int KB>
__global__ __launch_bounds__(256) void wgt_kernel(const float* __restrict__ csr_ea, int E,
                                                  const float* __restrict__ muA,
                                                  const float* __restrict__ sigA,
                                                  const float* __restrict__ muB,
                                                  const float* __restrict__ sigB,
                                                  float* __restrict__ wbuf) {
  int e = blockIdx.x * 256 + threadIdx.x;
  if (e >= E) return;
  const int KT = KA + KB;
  float p = csr_ea[e];
  float o[8];
#pragma unroll
  for (int k = 0; k < 8; ++k) o[k] = 0.f;
#pragma unroll
  for (int k = 0; k < KA; ++k) {
    float s = sigA[k];
    float d = p - muA[k];
    o[k] = __expf(-0.5f / (EPS_SIGMA + s * s) * d * d);
  }
#pragma unroll
  for (int k = 0; k < KB; ++k) {
    float s = sigB[k];
    float d = p - muB[k];
    o[KA + k] = __expf(-0.5f / (EPS_SIGMA + s * s) * d * d);
  }
  float4* w4 = (float4*)wbuf;
  w4[(size_t)e * 2 + 0] = make_float4(o[0], o[1], o[2], o[3]);
  w4[(size_t)e * 2 + 1] = make_float4(o[4], o[5], o[6], o[7]);
}

// --- aggregation with precomputed weights; wave per node, lane = channel ----
template <int KT>
__global__ __launch_bounds__(256) void agg_pre(const float* __restrict__ feat,
                                               const int* __restrict__ row_ptr,
                                               const int* __restrict__ csr_src,
                                               const float* __restrict__ wbuf,
                                               float* __restrict__ out, int n, int ldo) {
  int node = blockIdx.x * 4 + (threadIdx.x >> 6);
  int lane = threadIdx.x & 63;
  if (node >= n) return;
  int beg = row_ptr[node], end = row_ptr[node + 1];
  float acc[KT];
#pragma unroll
  for (int k = 0; k < KT; ++k) acc[k] = 0.f;
  const float4* w4 = (const float4*)wbuf;
  for (int i = beg; i < end; ++i) {
    int s = csr_src[i];
    float4 wa = w4[(size_t)i * 2 + 0];
    float4 wb = w4[(size_t)i * 2 + 1];
    float xv = feat[(size_t)s * 64 + lane];
    float w[8] = {wa.x, wa.y, wa.z, wa.w, wb.x, wb.y, wb.z, wb.w};
#pragma unroll
    for (int k = 0; k < KT; ++k) acc[k] = fmaf(w[k], xv, acc[k]);
  }
  int degi = end - beg;
  float invdeg = 1.0f / (float)(degi > 1 ? degi : 1);
  size_t o = (size_t)node * ldo + lane;
#pragma unroll
  for (int k = 0; k < KT; ++k) out[o + k * 64] = acc[k] * invdeg;
}

// --- weight prep: Bout[(K*64+64) x 64] = [rearranged G ; root] ---------------
__global__ void prep_cat(const float* __restrict__ g, const float* __restrict__ root,
                         float* __restrict__ Bout, int K) {
  int idx = blockIdx.x * 256 + threadIdx.x;
  int total = (K + 1) * 64 * 64;
  if (idx >= total) return;
  int r = idx >> 6, c = idx & 63;
  float v;
  if (r < K * 64) {
    int k = r >> 6, i = r & 63;
    v = g[i * (K * 64) + k * 64 + c];
  } else {
    v = root[(r - K * 64) * 64 + c];
  }
  Bout[idx] = v;
}

// ======================= GEMM building blocks (device) ======================
#define GEMM_COMPUTE(acc)                                              \
  {                                                                    \
    _Pragma("unroll") for (int k = 0; k < 64; k += 4) {                \
      float4 b0 = *(const float4*)&Bs[k + 0][tx * 4];                  \
      float4 b1v = *(const float4*)&Bs[k + 1][tx * 4];                 \
      float4 b2 = *(const float4*)&Bs[k + 2][tx * 4];                  \
      float4 b3 = *(const float4*)&Bs[k + 3][tx * 4];                  \
      _Pragma("unroll") for (int i = 0; i < 4; ++i) {                  \
        float4 a = *(const float4*)&As[ty * 4 + i][k];                 \
        acc[i][0] = fmaf(a.x, b0.x, acc[i][0]);                        \
        acc[i][1] = fmaf(a.x, b0.y, acc[i][1]);                        \
        acc[i][2] = fmaf(a.x, b0.z, acc[i][2]);                        \
        acc[i][3] = fmaf(a.x, b0.w, acc[i][3]);                        \
        acc[i][0] = fmaf(a.y, b1v.x, acc[i][0]);                       \
        acc[i][1] = fmaf(a.y, b1v.y, acc[i][1]);                       \
        acc[i][2] = fmaf(a.y, b1v.z, acc[i][2]);                       \
        acc[i][3] = fmaf(a.y, b1v.w, acc[i][3]);                       \
        acc[i][0] = fmaf(a.z, b2.x, acc[i][0]);                        \
        acc[i][1] = fmaf(a.z, b2.y, acc[i][1]);                        \
        acc[i][2] = fmaf(a.z, b2.z, acc[i][2]);                        \
        acc[i][3] = fmaf(a.z, b2.w, acc[i][3]);                        \
        acc[i][0] = fmaf(a.w, b3.x, acc[i][0]);                        \
        acc[i][1] = fmaf(a.w, b3.y, acc[i][1]);                        \
        acc[i][2] = fmaf(a.w, b3.z, acc[i][2]);                        \
        acc[i][3] = fmaf(a.w, b3.w, acc[i][3]);                        \
      }                                                                \
    }                                                                  \
  }

// --- dual GEMM: H = [agg1|x]@B1+b1 ; S = [aggsc|x]@B2+bs ; fused BN stats ---
__global__ __launch_bounds__(256) void gemm_dual(
    const float* __restrict__ A1, const float* __restrict__ x,
    const float* __restrict__ B1, const float* __restrict__ B2,
    const float* __restrict__ b1, const float* __restrict__ bs,
    float* __restrict__ H, float* __restrict__ S, int M,
    float* sumH, float* sqH, float* sumS, float* sqS) {
  __shared__ float As[64][68];
  __shared__ float Bs[64][64];
  __shared__ float red[16][64];
  int tile_m = blockIdx.x * 64;
  int tid = threadIdx.x, tx = tid & 15, ty = tid >> 4;
  float accH[4][4] = {}, accS[4][4] = {};

  auto stageA = [&](const float* Ap, int lda, int kb) {
#pragma unroll
    for (int i = 0; i < 4; ++i) {
      int idx = tid + i * 256, r = idx >> 4, c4 = idx & 15;
      float4 v = make_float4(0.f, 0.f, 0.f, 0.f);
      if (tile_m + r < M) v = *(const float4*)&Ap[(size_t)(tile_m + r) * lda + kb + c4 * 4];
      *(float4*)&As[r][c4 * 4] = v;
    }
  };
  auto stageB = [&](const float* Bp, int br) {
#pragma unroll
    for (int i = 0; i < 4; ++i) {
      int idx = tid + i * 256, r = idx >> 4, c4 = idx & 15;
      *(float4*)&Bs[r][c4 * 4] = *(const float4*)&Bp[(size_t)(br + r) * 64 + c4 * 4];
    }
  };

  for (int ch = 0; ch < 5; ++ch) {
    stageA(A1, 384, ch * 64);
    stageB(B1, ch * 64);
    __syncthreads();
    GEMM_COMPUTE(accH);
    __syncthreads();
  }
  stageA(A1, 384, 320);
  stageB(B2, 0);
  __syncthreads();
  GEMM_COMPUTE(accS);
  __syncthreads();
  stageA(x, 64, 0);
  stageB(B1, 320);
  __syncthreads();
  GEMM_COMPUTE(accH);
  __syncthreads();
  stageB(B2, 64);  // As still holds x
  __syncthreads();
  GEMM_COMPUTE(accS);
  __syncthreads();

  float csH[4] = {}, cqH[4] = {}, csS[4] = {}, cqS[4] = {};
#pragma unroll
  for (int i = 0; i < 4; ++i) {
    int r = tile_m + ty * 4 + i;
    if (r < M) {
      int cc = tx * 4;
      float ov[4], sv[4];
#pragma unroll
      for (int j = 0; j < 4; ++j) {
        ov[j] = accH[i][j] + b1[cc + j];
        sv[j] = accS[i][j] + bs[cc + j];
        csH[j] += ov[j];
        cqH[j] = fmaf(ov[j], ov[j], cqH[j]);
        csS[j] += sv[j];
        cqS[j] = fmaf(sv[j], sv[j], cqS[j]);
      }
      *(float4*)&H[(size_t)r * 64 + cc] = make_float4(ov[0], ov[1], ov[2], ov[3]);
      *(float4*)&S[(size_t)r * 64 + cc] = make_float4(sv[0], sv[1], sv[2], sv[3]);
    }
  }
  auto redadd = [&](const float v[4], float* dst) {
#pragma unroll
    for (int j = 0; j < 4; ++j) red[ty][tx * 4 + j] = v[j];
    __syncthreads();
    if (tid < 64) {
      float t = 0.f;
#pragma unroll
      for (int g = 0; g < 16; ++g) t += red[g][tid];
      atomicAdd(&dst[tid], t);
    }
    __syncthreads();
  };
  redadd(csH, sumH);
  redadd(cqH, sqH);
  redadd(csS, sumS);
  redadd(cqS, sqS);
}

// --- single GEMM: C = [A1(K1)|A2(64)]@B + bias ; fused BN stats -------------
__global__ __launch_bounds__(256) void gemm_fused(const float* __restrict__ A1, int lda1,
                                                  int K1, const float* __restrict__ A2,
                                                  const float* __restrict__ B,
                                                  const float* __restrict__ bias,
                                                  float* __restrict__ C, int M,
                                                  float* sums, float* sumsq) {
  __shared__ float As[64][68];
  __shared__ float Bs[64][64];
  __shared__ float red[16][64];
  int tile_m = blockIdx.x * 64;
  int tid = threadIdx.x, tx = tid & 15, ty = tid >> 4;
  float acc[4][4] = {};
  int nch = K1 >> 6;
  for (int ch = 0; ch <= nch; ++ch) {
    const float* Ap;
    int lda, kb;
    if (ch < nch) { Ap = A1; lda = lda1; kb = ch * 64; }
    else          { Ap = A2; lda = 64;   kb = 0; }
#pragma unroll
    for (int i = 0; i < 4; ++i) {
      int idx = tid + i * 256, r = idx >> 4, c4 = idx & 15;
      float4 v = make_float4(0.f, 0.f, 0.f, 0.f);
      if (tile_m + r < M) v = *(const float4*)&Ap[(size_t)(tile_m + r) * lda + kb + c4 * 4];
      *(float4*)&As[r][c4 * 4] = v;
      *(float4*)&Bs[r][c4 * 4] = *(const float4*)&B[(size_t)(ch * 64 + r) * 64 + c4 * 4];
    }
    __syncthreads();
    GEMM_COMPUTE(acc);
    __syncthreads();
  }
  float cs[4] = {}, cq[4] = {};
#pragma unroll
  for (int i = 0; i < 4; ++i) {
    int r = tile_m + ty * 4 + i;
    if (r < M) {
      int cc = tx * 4;
      float ov[4];
#pragma unroll
      for (int j = 0; j < 4; ++j) {
        ov[j] = acc[i][j] + bias[cc + j];
        cs[j] += ov[j];
        cq[j] = fmaf(ov[j], ov[j], cq[j]);
      }
      *(float4*)&C[(size_t)r * 64 + cc] = make_float4(ov[0], ov[1], ov[2], ov[3]);
    }
  }
#pragma unroll
  for (int j = 0; j < 4; ++j) red[ty][tx * 4 + j] = cs[j];
  __syncthreads();
  if (tid < 64) {
    float t = 0.f;
#pragma unroll
    for (int g = 0; g < 16; ++g) t += red[g][tid];
    atomicAdd(&sums[tid], t);
  }
  __syncthreads();
#pragma unroll
  for (int j = 0; j < 4; ++j) red[ty][tx * 4 + j] = cq[j];
  __syncthreads();
  if (tid < 64) {
    float t = 0.f;
#pragma unroll
    for (int g = 0; g < 16; ++g) t += red[g][tid];
    atomicAdd(&sumsq[tid], t);
  }
}

// --- batchnorm scale/shift + epilogues --------------------------------------
__global__ void bn_final(const float* sum, const float* sumsq, const float* gamma,
                         const float* beta, int n, float* scale, float* shift) {
  int c = threadIdx.x;
  float m = sum[c] / (float)n;
  float v = sumsq[c] / (float)n - m * m;
  float r = rsqrtf(v + BN_EPS);
  float s = r * gamma[c];
  scale[c] = s;
  shift[c] = beta[c] - m * s;
}

__global__ void norm_elu(float* h, const float* __restrict__ scale,
                         const float* __restrict__ shift, int total) {
  int i = blockIdx.x * 256 + threadIdx.x;
  if (i >= total) return;
  int c = i & 63;
  float v = h[i] * scale[c] + shift[c];
  h[i] = v > 0.f ? v : expm1f(v);
}

__global__ void final_kernel(const float* __restrict__ h2, const float* __restrict__ sc,
                             const float* __restrict__ s2, const float* __restrict__ t2,
                             const float* __restrict__ ss, const float* __restrict__ ts,
                             float* __restrict__ out, int total) {
  int i = blockIdx.x * 256 + threadIdx.x;
  if (i >= total) return;
  int c = i & 63;
  float v = h2[i] * s2[c] + t2[c] + sc[i] * ss[c] + ts[c];
  out[i] = v > 0.f ? v : expm1f(v);
}

// ---------------------------------------------------------------------------
extern "C" void kernel_launch(void* const* d_in, const int* in_sizes, int n_in,
                              void* d_out, int out_size, void* d_ws, size_t ws_size,
                              hipStream_t stream) {
  const float* x    = (const float*)d_in[0];
  const void*  ei   = d_in[1];
  const float* ea   = (const float*)d_in[2];
  const float* g1   = (const float*)d_in[3];
  const float* mu1  = (const float*)d_in[4];
  const float* sig1 = (const float*)d_in[5];
  const float* root1= (const float*)d_in[6];
  const float* b1   = (const float*)d_in[7];
  const float* gam1 = (const float*)d_in[8];
  const float* bet1 = (const float*)d_in[9];
  const float* g2   = (const float*)d_in[10];
  const float* mu2  = (const float*)d_in[11];
  const float* sig2 = (const float*)d_in[12];
  const float* root2= (const float*)d_in[13];
  const float* b2   = (const float*)d_in[14];
  const float* gam2 = (const float*)d_in[15];
  const float* bet2 = (const float*)d_in[16];
  const float* gs   = (const float*)d_in[17];
  const float* mus  = (const float*)d_in[18];
  const float* sigs = (const float*)d_in[19];
  const float* roots= (const float*)d_in[20];
  const float* bs   = (const float*)d_in[21];
  const float* gams = (const float*)d_in[22];
  const float* bets = (const float*)d_in[23];

  int N = in_sizes[0] / 64;
  int E = in_sizes[1] / 2;

  char* w = (char*)d_ws;
  auto alloc = [&](size_t bytes) {
    char* p = w;
    w += (bytes + 255) & ~(size_t)255;
    return p;
  };
  int*   flag    = (int*)alloc(256);
  int*   cnt     = (int*)alloc((size_t)N * 4);
  int*   row_ptr = (int*)alloc((size_t)(N + 1) * 4);
  int*   partials= (int*)alloc(256 * 4);
  int*   csr_src = (int*)alloc((size_t)E * 4);
  float* csr_ea  = (float*)alloc((size_t)E * 4);
  float* wbuf    = (float*)alloc((size_t)E * 8 * 4);    // [E][8] gaussian weights
  float* Abuf    = (float*)alloc((size_t)N * 384 * 4);  // agg outputs
  float* h       = (float*)alloc((size_t)N * 64 * 4);
  float* h2      = (float*)alloc((size_t)N * 64 * 4);
  float* scb     = (float*)alloc((size_t)N * 64 * 4);
  float* B1cat   = (float*)alloc(384 * 64 * 4);
  float* B2cat   = (float*)alloc(384 * 64 * 4);
  float* Bsc     = (float*)alloc(128 * 64 * 4);
  float* stats   = (float*)alloc(12 * 64 * 4);

  hipMemsetAsync(cnt, 0, (size_t)N * 4, stream);
  hipMemsetAsync(stats, 0, 12 * 64 * 4, stream);

  int eb = (E + 255) / 256;
  int nb1 = (N + 2047) / 2048;

  prep_cat<<<(6 * 4096 + 255) / 256, 256, 0, stream>>>(g1, root1, B1cat, 5);
  prep_cat<<<(6 * 4096 + 255) / 256, 256, 0, stream>>>(g2, root2, B2cat, 5);
  prep_cat<<<(2 * 4096 + 255) / 256, 256, 0, stream>>>(gs, roots, Bsc, 1);

  detect_kernel<<<1, 1, 0, stream>>>(ei, flag);
  hist_kernel<<<eb, 256, 0, stream>>>(ei, E, flag, cnt);
  scan1<<<nb1, 256, 0, stream>>>(cnt, row_ptr, partials, N);
  scan2<<<1, 256, 0, stream>>>(partials, nb1, row_ptr, N);
  scan3<<<(N + 255) / 256, 256, 0, stream>>>(row_ptr, partials, cnt, N);
  scatter_kernel<<<eb, 256, 0, stream>>>(ei, ea, E, flag, row_ptr, cnt, csr_src, csr_ea);

  int mtiles = (N + 63) / 64;
  int nb_node = (N + 3) / 4;
  int nb_elem = (N * 64 + 255) / 256;

  // ---- layer1 + shortcut ----
  wgt_kernel<5, 1><<<eb, 256, 0, stream>>>(csr_ea, E, mu1, sig1, mus, sigs, wbuf);
  agg_pre<6><<<nb_node, 256, 0, stream>>>(x, row_ptr, csr_src, wbuf, Abuf, N, 384);
  gemm_dual<<<mtiles, 256, 0, stream>>>(Abuf, x, B1cat, Bsc, b1, bs, h, scb, N,
                                        stats + 0 * 64, stats + 1 * 64,
                                        stats + 4 * 64, stats + 5 * 64);
  bn_final<<<1, 64, 0, stream>>>(stats + 0 * 64, stats + 1 * 64, gam1, bet1, N,
                                 stats + 6 * 64, stats + 7 * 64);
  norm_elu<<<nb_elem, 256, 0, stream>>>(h, stats + 6 * 64, stats + 7 * 64, N * 64);

  // ---- layer2 ----
  wgt_kernel<5, 0><<<eb, 256, 0, stream>>>(csr_ea, E, mu2, sig2, nullptr, nullptr, wbuf);
  agg_pre<5><<<nb_node, 256, 0, stream>>>(h, row_ptr, csr_src, wbuf, Abuf, N, 320);
  gemm_fused<<<mtiles, 256, 0, stream>>>(Abuf, 320, 320, h, B2cat, b2, h2, N,
                                         stats + 2 * 64, stats + 3 * 64);

  bn_final<<<1, 64, 0, stream>>>(stats + 2 * 64, stats + 3 * 64, gam2, bet2, N,
                                 stats + 8 * 64, stats + 9 * 64);
  bn_final<<<1, 64, 0, stream>>>(stats + 4 * 64, stats + 5 * 64, gams, bets, N,
                                 stats + 10 * 64, stats + 11 * 64);

  final_kernel<<<nb_elem, 256, 0, stream>>>(h2, scb, stats + 8 * 64, stats + 9 * 64,
                                            stats + 10 * 64, stats + 11 * 64,
                                            (float*)d_out, N * 64);
}

// Round 4
// 485.113 us; speedup vs baseline: 2.7703x; 2.7703x over previous
//
#include <hip/hip_runtime.h>
#include <hip/hip_bf16.h>

// ---------------------------------------------------------------------------
// ResidualBlock: GMMConv(x)->BN->ELU->GMMConv->BN  +  GMMConv_sc(x)->BN ; ELU
// N=50000, E=800000, C=64, K_main=5, K_sc=1. fp32.
// Round 4: round-3's wgt-precompute + agg_pre kept; gemm_dual REVERTED to
// three single-accumulator gemm_fused launches (round-3 dual spilled: 256
// VGPR, 1 GB scratch FETCH, 940us). BN stats stay fused in GEMM epilogues.
// ---------------------------------------------------------------------------

#define EPS_SIGMA 1e-15f
#define BN_EPS    1e-5f

// --- dtype detect: int64 edge_index has all-zero high words -----------------
__global__ void detect_kernel(const void* ei, int* flag) {
  const int* p = (const int*)ei;
  int allzero = 1;
  for (int i = 1; i < 512; i += 2) {
    if (p[i] != 0) { allzero = 0; break; }
  }
  *flag = allzero;  // 1 => int64 layout, 0 => int32 layout
}

__device__ __forceinline__ int load_idx(const void* ei, size_t pos, int is64) {
  if (is64) return (int)((const long long*)ei)[pos];
  return ((const int*)ei)[pos];
}

// --- CSR build ---------------------------------------------------------------
__global__ void hist_kernel(const void* ei, int E, const int* flag, int* cnt) {
  int e = blockIdx.x * blockDim.x + threadIdx.x;
  if (e >= E) return;
  int d = load_idx(ei, (size_t)E + e, *flag);
  atomicAdd(&cnt[d], 1);
}

__global__ __launch_bounds__(256) void scan1(const int* __restrict__ cnt,
                                             int* __restrict__ row_ptr,
                                             int* __restrict__ partials, int n) {
  int tid = threadIdx.x;
  int base = blockIdx.x * 2048 + tid * 8;
  int v[8], pre[8];
  int run = 0;
#pragma unroll
  for (int j = 0; j < 8; ++j) {
    int idx = base + j;
    v[j] = (idx < n) ? cnt[idx] : 0;
    pre[j] = run;
    run += v[j];
  }
  __shared__ int sd[256];
  sd[tid] = run;
  __syncthreads();
  for (int off = 1; off < 256; off <<= 1) {
    int t = (tid >= off) ? sd[tid - off] : 0;
    __syncthreads();
    sd[tid] += t;
    __syncthreads();
  }
  int excl = sd[tid] - run;
#pragma unroll
  for (int j = 0; j < 8; ++j) {
    int idx = base + j;
    if (idx < n) row_ptr[idx] = excl + pre[j];
  }
  if (tid == 255) partials[blockIdx.x] = sd[255];
}

__global__ void scan2(int* partials, int nb, int* row_ptr, int n) {
  __shared__ int sd[256];
  int tid = threadIdx.x;
  int v = (tid < nb) ? partials[tid] : 0;
  sd[tid] = v;
  __syncthreads();
  for (int off = 1; off < 256; off <<= 1) {
    int t = (tid >= off) ? sd[tid - off] : 0;
    __syncthreads();
    sd[tid] += t;
    __syncthreads();
  }
  if (tid < nb) partials[tid] = sd[tid] - v;
  if (tid == nb - 1) row_ptr[n] = sd[tid];
}

__global__ void scan3(int* __restrict__ row_ptr, const int* __restrict__ partials,
                      int* __restrict__ cnt, int n) {
  int i = blockIdx.x * 256 + threadIdx.x;
  if (i < n) {
    row_ptr[i] += partials[i >> 11];
    cnt[i] = 0;
  }
}

__global__ void scatter_kernel(const void* ei, const float* __restrict__ ea, int E,
                               const int* flag, const int* __restrict__ row_ptr,
                               int* cursor, int* __restrict__ csr_src,
                               float* __restrict__ csr_ea) {
  int e = blockIdx.x * blockDim.x + threadIdx.x;
  if (e >= E) return;
  int is64 = *flag;
  int s = load_idx(ei, (size_t)e, is64);
  int d = load_idx(ei, (size_t)E + e, is64);
  int pos = atomicAdd(&cursor[d], 1);
  int slot = row_ptr[d] + pos;
  csr_src[slot] = s;
  csr_ea[slot] = ea[e];
}

// --- edge-parallel gaussian weights: wbuf[e][0..7] (padded AoS) -------------
template <int KA, int KB>
__global__ __launch_bounds__(256) void wgt_kernel(const float* __restrict__ csr_ea, int E,
                                                  const float* __restrict__ muA,
                                                  const float* __restrict__ sigA,
                                                  const float* __restrict__ muB,
                                                  const float* __restrict__ sigB,
                                                  float* __restrict__ wbuf) {
  int e = blockIdx.x * 256 + threadIdx.x;
  if (e >= E) return;
  float p = csr_ea[e];
  float o[8];
#pragma unroll
  for (int k = 0; k < 8; ++k) o[k] = 0.f;
#pragma unroll
  for (int k = 0; k < KA; ++k) {
    float s = sigA[k];
    float d = p - muA[k];
    o[k] = __expf(-0.5f / (EPS_SIGMA + s * s) * d * d);
  }
#pragma unroll
  for (int k = 0; k < KB; ++k) {
    float s = sigB[k];
    float d = p - muB[k];
    o[KA + k] = __expf(-0.5f / (EPS_SIGMA + s * s) * d * d);
  }
  float4* w4 = (float4*)wbuf;
  w4[(size_t)e * 2 + 0] = make_float4(o[0], o[1], o[2], o[3]);
  w4[(size_t)e * 2 + 1] = make_float4(o[4], o[5], o[6], o[7]);
}

// --- aggregation with precomputed weights; wave per node, lane = channel ----
template <int KT>
__global__ __launch_bounds__(256) void agg_pre(const float* __restrict__ feat,
                                               const int* __restrict__ row_ptr,
                                               const int* __restrict__ csr_src,
                                               const float* __restrict__ wbuf,
                                               float* __restrict__ out, int n, int ldo) {
  int node = blockIdx.x * 4 + (threadIdx.x >> 6);
  int lane = threadIdx.x & 63;
  if (node >= n) return;
  int beg = row_ptr[node], end = row_ptr[node + 1];
  float acc[KT];
#pragma unroll
  for (int k = 0; k < KT; ++k) acc[k] = 0.f;
  const float4* w4 = (const float4*)wbuf;
  for (int i = beg; i < end; ++i) {
    int s = csr_src[i];
    float4 wa = w4[(size_t)i * 2 + 0];
    float4 wb = w4[(size_t)i * 2 + 1];
    float xv = feat[(size_t)s * 64 + lane];
    float w[8] = {wa.x, wa.y, wa.z, wa.w, wb.x, wb.y, wb.z, wb.w};
#pragma unroll
    for (int k = 0; k < KT; ++k) acc[k] = fmaf(w[k], xv, acc[k]);
  }
  int degi = end - beg;
  float invdeg = 1.0f / (float)(degi > 1 ? degi : 1);
  size_t o = (size_t)node * ldo + lane;
#pragma unroll
  for (int k = 0; k < KT; ++k) out[o + k * 64] = acc[k] * invdeg;
}

// --- weight prep: Bout[(K*64+64) x 64] = [rearranged G ; root] ---------------
__global__ void prep_cat(const float* __restrict__ g, const float* __restrict__ root,
                         float* __restrict__ Bout, int K) {
  int idx = blockIdx.x * 256 + threadIdx.x;
  int total = (K + 1) * 64 * 64;
  if (idx >= total) return;
  int r = idx >> 6, c = idx & 63;
  float v;
  if (r < K * 64) {
    int k = r >> 6, i = r & 63;
    v = g[i * (K * 64) + k * 64 + c];
  } else {
    v = root[(r - K * 64) * 64 + c];
  }
  Bout[idx] = v;
}

// --- single GEMM: C = [A1(K1)|A2(64)]@B + bias ; fused BN stats -------------
__global__ __launch_bounds__(256) void gemm_fused(const float* __restrict__ A1, int lda1,
                                                  int K1, const float* __restrict__ A2,
                                                  const float* __restrict__ B,
                                                  const float* __restrict__ bias,
                                                  float* __restrict__ C, int M,
                                                  float* sums, float* sumsq) {
  __shared__ float As[64][68];
  __shared__ float Bs[64][64];
  __shared__ float red[16][64];
  int tile_m = blockIdx.x * 64;
  int tid = threadIdx.x, tx = tid & 15, ty = tid >> 4;
  float acc[4][4] = {};
  int nch = K1 >> 6;
  for (int ch = 0; ch <= nch; ++ch) {
    const float* Ap;
    int lda, kb;
    if (ch < nch) { Ap = A1; lda = lda1; kb = ch * 64; }
    else          { Ap = A2; lda = 64;   kb = 0; }
#pragma unroll
    for (int i = 0; i < 4; ++i) {
      int idx = tid + i * 256, r = idx >> 4, c4 = idx & 15;
      float4 v = make_float4(0.f, 0.f, 0.f, 0.f);
      if (tile_m + r < M) v = *(const float4*)&Ap[(size_t)(tile_m + r) * lda + kb + c4 * 4];
      *(float4*)&As[r][c4 * 4] = v;
      *(float4*)&Bs[r][c4 * 4] = *(const float4*)&B[(size_t)(ch * 64 + r) * 64 + c4 * 4];
    }
    __syncthreads();
#pragma unroll
    for (int k = 0; k < 64; k += 4) {
      float4 b0 = *(const float4*)&Bs[k + 0][tx * 4];
      float4 b1v = *(const float4*)&Bs[k + 1][tx * 4];
      float4 b2 = *(const float4*)&Bs[k + 2][tx * 4];
      float4 b3 = *(const float4*)&Bs[k + 3][tx * 4];
#pragma unroll
      for (int i = 0; i < 4; ++i) {
        float4 a = *(const float4*)&As[ty * 4 + i][k];
        acc[i][0] = fmaf(a.x, b0.x, acc[i][0]);
        acc[i][1] = fmaf(a.x, b0.y, acc[i][1]);
        acc[i][2] = fmaf(a.x, b0.z, acc[i][2]);
        acc[i][3] = fmaf(a.x, b0.w, acc[i][3]);
        acc[i][0] = fmaf(a.y, b1v.x, acc[i][0]);
        acc[i][1] = fmaf(a.y, b1v.y, acc[i][1]);
        acc[i][2] = fmaf(a.y, b1v.z, acc[i][2]);
        acc[i][3] = fmaf(a.y, b1v.w, acc[i][3]);
        acc[i][0] = fmaf(a.z, b2.x, acc[i][0]);
        acc[i][1] = fmaf(a.z, b2.y, acc[i][1]);
        acc[i][2] = fmaf(a.z, b2.z, acc[i][2]);
        acc[i][3] = fmaf(a.z, b2.w, acc[i][3]);
        acc[i][0] = fmaf(a.w, b3.x, acc[i][0]);
        acc[i][1] = fmaf(a.w, b3.y, acc[i][1]);
        acc[i][2] = fmaf(a.w, b3.z, acc[i][2]);
        acc[i][3] = fmaf(a.w, b3.w, acc[i][3]);
      }
    }
    __syncthreads();
  }
  float cs[4] = {}, cq[4] = {};
#pragma unroll
  for (int i = 0; i < 4; ++i) {
    int r = tile_m + ty * 4 + i;
    if (r < M) {
      int cc = tx * 4;
      float ov[4];
#pragma unroll
      for (int j = 0; j < 4; ++j) {
        ov[j] = acc[i][j] + bias[cc + j];
        cs[j] += ov[j];
        cq[j] = fmaf(ov[j], ov[j], cq[j]);
      }
      *(float4*)&C[(size_t)r * 64 + cc] = make_float4(ov[0], ov[1], ov[2], ov[3]);
    }
  }
#pragma unroll
  for (int j = 0; j < 4; ++j) red[ty][tx * 4 + j] = cs[j];
  __syncthreads();
  if (tid < 64) {
    float t = 0.f;
#pragma unroll
    for (int g = 0; g < 16; ++g) t += red[g][tid];
    atomicAdd(&sums[tid], t);
  }
  __syncthreads();
#pragma unroll
  for (int j = 0; j < 4; ++j) red[ty][tx * 4 + j] = cq[j];
  __syncthreads();
  if (tid < 64) {
    float t = 0.f;
#pragma unroll
    for (int g = 0; g < 16; ++g) t += red[g][tid];
    atomicAdd(&sumsq[tid], t);
  }
}

// --- batchnorm scale/shift + epilogues --------------------------------------
__global__ void bn_final(const float* sum, const float* sumsq, const float* gamma,
                         const float* beta, int n, float* scale, float* shift) {
  int c = threadIdx.x;
  float m = sum[c] / (float)n;
  float v = sumsq[c] / (float)n - m * m;
  float r = rsqrtf(v + BN_EPS);
  float s = r * gamma[c];
  scale[c] = s;
  shift[c] = beta[c] - m * s;
}

__global__ void norm_elu(float* h, const float* __restrict__ scale,
                         const float* __restrict__ shift, int total) {
  int i = blockIdx.x * 256 + threadIdx.x;
  if (i >= total) return;
  int c = i & 63;
  float v = h[i] * scale[c] + shift[c];
  h[i] = v > 0.f ? v : expm1f(v);
}

__global__ void final_kernel(const float* __restrict__ h2, const float* __restrict__ sc,
                             const float* __restrict__ s2, const float* __restrict__ t2,
                             const float* __restrict__ ss, const float* __restrict__ ts,
                             float* __restrict__ out, int total) {
  int i = blockIdx.x * 256 + threadIdx.x;
  if (i >= total) return;
  int c = i & 63;
  float v = h2[i] * s2[c] + t2[c] + sc[i] * ss[c] + ts[c];
  out[i] = v > 0.f ? v : expm1f(v);
}

// ---------------------------------------------------------------------------
extern "C" void kernel_launch(void* const* d_in, const int* in_sizes, int n_in,
                              void* d_out, int out_size, void* d_ws, size_t ws_size,
                              hipStream_t stream) {
  const float* x    = (const float*)d_in[0];
  const void*  ei   = d_in[1];
  const float* ea   = (const float*)d_in[2];
  const float* g1   = (const float*)d_in[3];
  const float* mu1  = (const float*)d_in[4];
  const float* sig1 = (const float*)d_in[5];
  const float* root1= (const float*)d_in[6];
  const float* b1   = (const float*)d_in[7];
  const float* gam1 = (const float*)d_in[8];
  const float* bet1 = (const float*)d_in[9];
  const float* g2   = (const float*)d_in[10];
  const float* mu2  = (const float*)d_in[11];
  const float* sig2 = (const float*)d_in[12];
  const float* root2= (const float*)d_in[13];
  const float* b2   = (const float*)d_in[14];
  const float* gam2 = (const float*)d_in[15];
  const float* bet2 = (const float*)d_in[16];
  const float* gs   = (const float*)d_in[17];
  const float* mus  = (const float*)d_in[18];
  const float* sigs = (const float*)d_in[19];
  const float* roots= (const float*)d_in[20];
  const float* bs   = (const float*)d_in[21];
  const float* gams = (const float*)d_in[22];
  const float* bets = (const float*)d_in[23];

  int N = in_sizes[0] / 64;
  int E = in_sizes[1] / 2;

  char* w = (char*)d_ws;
  auto alloc = [&](size_t bytes) {
    char* p = w;
    w += (bytes + 255) & ~(size_t)255;
    return p;
  };
  int*   flag    = (int*)alloc(256);
  int*   cnt     = (int*)alloc((size_t)N * 4);
  int*   row_ptr = (int*)alloc((size_t)(N + 1) * 4);
  int*   partials= (int*)alloc(256 * 4);
  int*   csr_src = (int*)alloc((size_t)E * 4);
  float* csr_ea  = (float*)alloc((size_t)E * 4);
  float* wbuf    = (float*)alloc((size_t)E * 8 * 4);    // [E][8] gaussian weights
  float* Abuf    = (float*)alloc((size_t)N * 384 * 4);  // agg outputs
  float* h       = (float*)alloc((size_t)N * 64 * 4);
  float* h2      = (float*)alloc((size_t)N * 64 * 4);
  float* scb     = (float*)alloc((size_t)N * 64 * 4);
  float* B1cat   = (float*)alloc(384 * 64 * 4);
  float* B2cat   = (float*)alloc(384 * 64 * 4);
  float* Bsc     = (float*)alloc(128 * 64 * 4);
  float* stats   = (float*)alloc(12 * 64 * 4);

  hipMemsetAsync(cnt, 0, (size_t)N * 4, stream);
  hipMemsetAsync(stats, 0, 12 * 64 * 4, stream);

  int eb = (E + 255) / 256;
  int nb1 = (N + 2047) / 2048;

  prep_cat<<<(6 * 4096 + 255) / 256, 256, 0, stream>>>(g1, root1, B1cat, 5);
  prep_cat<<<(6 * 4096 + 255) / 256, 256, 0, stream>>>(g2, root2, B2cat, 5);
  prep_cat<<<(2 * 4096 + 255) / 256, 256, 0, stream>>>(gs, roots, Bsc, 1);

  detect_kernel<<<1, 1, 0, stream>>>(ei, flag);
  hist_kernel<<<eb, 256, 0, stream>>>(ei, E, flag, cnt);
  scan1<<<nb1, 256, 0, stream>>>(cnt, row_ptr, partials, N);
  scan2<<<1, 256, 0, stream>>>(partials, nb1, row_ptr, N);
  scan3<<<(N + 255) / 256, 256, 0, stream>>>(row_ptr, partials, cnt, N);
  scatter_kernel<<<eb, 256, 0, stream>>>(ei, ea, E, flag, row_ptr, cnt, csr_src, csr_ea);

  int mtiles = (N + 63) / 64;
  int nb_node = (N + 3) / 4;
  int nb_elem = (N * 64 + 255) / 256;

  // ---- layer1 + shortcut ----
  wgt_kernel<5, 1><<<eb, 256, 0, stream>>>(csr_ea, E, mu1, sig1, mus, sigs, wbuf);
  agg_pre<6><<<nb_node, 256, 0, stream>>>(x, row_ptr, csr_src, wbuf, Abuf, N, 384);
  // h = [agg1 | x] @ [G1r; root1] + b1   (+BN1 stats)
  gemm_fused<<<mtiles, 256, 0, stream>>>(Abuf, 384, 320, x, B1cat, b1, h, N,
                                         stats + 0 * 64, stats + 1 * 64);
  // scb = [aggsc | x] @ [gs; roots] + bs (+BNsc stats)
  gemm_fused<<<mtiles, 256, 0, stream>>>(Abuf + 320, 384, 64, x, Bsc, bs, scb, N,
                                         stats + 4 * 64, stats + 5 * 64);
  bn_final<<<1, 64, 0, stream>>>(stats + 0 * 64, stats + 1 * 64, gam1, bet1, N,
                                 stats + 6 * 64, stats + 7 * 64);
  norm_elu<<<nb_elem, 256, 0, stream>>>(h, stats + 6 * 64, stats + 7 * 64, N * 64);

  // ---- layer2 ----
  wgt_kernel<5, 0><<<eb, 256, 0, stream>>>(csr_ea, E, mu2, sig2, nullptr, nullptr, wbuf);
  agg_pre<5><<<nb_node, 256, 0, stream>>>(h, row_ptr, csr_src, wbuf, Abuf, N, 320);
  gemm_fused<<<mtiles, 256, 0, stream>>>(Abuf, 320, 320, h, B2cat, b2, h2, N,
                                         stats + 2 * 64, stats + 3 * 64);

  bn_final<<<1, 64, 0, stream>>>(stats + 2 * 64, stats + 3 * 64, gam2, bet2, N,
                                 stats + 8 * 64, stats + 9 * 64);
  bn_final<<<1, 64, 0, stream>>>(stats + 4 * 64, stats + 5 * 64, gams, bets, N,
                                 stats + 10 * 64, stats + 11 * 64);

  final_kernel<<<nb_elem, 256, 0, stream>>>(h2, scb, stats + 8 * 64, stats + 9 * 64,
                                            stats + 10 * 64, stats + 11 * 64,
                                            (float*)d_out, N * 64);
}

// Round 5
// 409.424 us; speedup vs baseline: 3.2824x; 1.1849x over previous
//
#include <hip/hip_runtime.h>
#include <hip/hip_bf16.h>

// ---------------------------------------------------------------------------
// ResidualBlock: GMMConv(x)->BN->ELU->GMMConv->BN  +  GMMConv_sc(x)->BN ; ELU
// N=50000, E=800000, C=64, K_main=5, K_sc=1. fp32.
// Round 5: agg was LATENCY-bound (VALUBusy 17%, HBM 23%, dur unchanged when
// exp removed). Fix: pack {w[6], src} into one 32B record; unroll edge loop
// x4 so 4 gathers are in flight per wave (4x MLP).
// ---------------------------------------------------------------------------

#define EPS_SIGMA 1e-15f
#define BN_EPS    1e-5f

// --- dtype detect: int64 edge_index has all-zero high words -----------------
__global__ void detect_kernel(const void* ei, int* flag) {
  const int* p = (const int*)ei;
  int allzero = 1;
  for (int i = 1; i < 512; i += 2) {
    if (p[i] != 0) { allzero = 0; break; }
  }
  *flag = allzero;  // 1 => int64 layout, 0 => int32 layout
}

__device__ __forceinline__ int load_idx(const void* ei, size_t pos, int is64) {
  if (is64) return (int)((const long long*)ei)[pos];
  return ((const int*)ei)[pos];
}

// --- CSR build ---------------------------------------------------------------
__global__ void hist_kernel(const void* ei, int E, const int* flag, int* cnt) {
  int e = blockIdx.x * blockDim.x + threadIdx.x;
  if (e >= E) return;
  int d = load_idx(ei, (size_t)E + e, *flag);
  atomicAdd(&cnt[d], 1);
}

__global__ __launch_bounds__(256) void scan1(const int* __restrict__ cnt,
                                             int* __restrict__ row_ptr,
                                             int* __restrict__ partials, int n) {
  int tid = threadIdx.x;
  int base = blockIdx.x * 2048 + tid * 8;
  int v[8], pre[8];
  int run = 0;
#pragma unroll
  for (int j = 0; j < 8; ++j) {
    int idx = base + j;
    v[j] = (idx < n) ? cnt[idx] : 0;
    pre[j] = run;
    run += v[j];
  }
  __shared__ int sd[256];
  sd[tid] = run;
  __syncthreads();
  for (int off = 1; off < 256; off <<= 1) {
    int t = (tid >= off) ? sd[tid - off] : 0;
    __syncthreads();
    sd[tid] += t;
    __syncthreads();
  }
  int excl = sd[tid] - run;
#pragma unroll
  for (int j = 0; j < 8; ++j) {
    int idx = base + j;
    if (idx < n) row_ptr[idx] = excl + pre[j];
  }
  if (tid == 255) partials[blockIdx.x] = sd[255];
}

__global__ void scan2(int* partials, int nb, int* row_ptr, int n) {
  __shared__ int sd[256];
  int tid = threadIdx.x;
  int v = (tid < nb) ? partials[tid] : 0;
  sd[tid] = v;
  __syncthreads();
  for (int off = 1; off < 256; off <<= 1) {
    int t = (tid >= off) ? sd[tid - off] : 0;
    __syncthreads();
    sd[tid] += t;
    __syncthreads();
  }
  if (tid < nb) partials[tid] = sd[tid] - v;
  if (tid == nb - 1) row_ptr[n] = sd[tid];
}

__global__ void scan3(int* __restrict__ row_ptr, const int* __restrict__ partials,
                      int* __restrict__ cnt, int n) {
  int i = blockIdx.x * 256 + threadIdx.x;
  if (i < n) {
    row_ptr[i] += partials[i >> 11];
    cnt[i] = 0;
  }
}

__global__ void scatter_kernel(const void* ei, const float* __restrict__ ea, int E,
                               const int* flag, const int* __restrict__ row_ptr,
                               int* cursor, int* __restrict__ csr_src,
                               float* __restrict__ csr_ea) {
  int e = blockIdx.x * blockDim.x + threadIdx.x;
  if (e >= E) return;
  int is64 = *flag;
  int s = load_idx(ei, (size_t)e, is64);
  int d = load_idx(ei, (size_t)E + e, is64);
  int pos = atomicAdd(&cursor[d], 1);
  int slot = row_ptr[d] + pos;
  csr_src[slot] = s;
  csr_ea[slot] = ea[e];
}

// --- edge records: {w0..w5, src_bits, 0} per edge (32B) ---------------------
template <int KA, int KB>
__global__ __launch_bounds__(256) void wgt_kernel(const float* __restrict__ csr_ea,
                                                  const int* __restrict__ csr_src, int E,
                                                  const float* __restrict__ muA,
                                                  const float* __restrict__ sigA,
                                                  const float* __restrict__ muB,
                                                  const float* __restrict__ sigB,
                                                  float* __restrict__ wbuf) {
  int e = blockIdx.x * 256 + threadIdx.x;
  if (e >= E) return;
  float p = csr_ea[e];
  float o[8];
#pragma unroll
  for (int k = 0; k < 8; ++k) o[k] = 0.f;
#pragma unroll
  for (int k = 0; k < KA; ++k) {
    float s = sigA[k];
    float d = p - muA[k];
    o[k] = __expf(-0.5f / (EPS_SIGMA + s * s) * d * d);
  }
#pragma unroll
  for (int k = 0; k < KB; ++k) {
    float s = sigB[k];
    float d = p - muB[k];
    o[KA + k] = __expf(-0.5f / (EPS_SIGMA + s * s) * d * d);
  }
  o[6] = __int_as_float(csr_src[e]);
  float4* w4 = (float4*)wbuf;
  w4[(size_t)e * 2 + 0] = make_float4(o[0], o[1], o[2], o[3]);
  w4[(size_t)e * 2 + 1] = make_float4(o[4], o[5], o[6], o[7]);
}

// --- aggregation: wave per node, lane = channel, 4 edges in flight ----------
// weights for edge: wa.xyzw = w0..w3, wb.xy = w4,w5, wb.z = src bits
template <int KT>
__device__ __forceinline__ void agg_fma(float* acc, float4 wa, float4 wb, float xv) {
  acc[0] = fmaf(wa.x, xv, acc[0]);
  if (KT > 1) acc[1] = fmaf(wa.y, xv, acc[1]);
  if (KT > 2) acc[2] = fmaf(wa.z, xv, acc[2]);
  if (KT > 3) acc[3] = fmaf(wa.w, xv, acc[3]);
  if (KT > 4) acc[4] = fmaf(wb.x, xv, acc[4]);
  if (KT > 5) acc[5] = fmaf(wb.y, xv, acc[5]);
}

template <int KT>
__global__ __launch_bounds__(256) void agg_pre(const float* __restrict__ feat,
                                               const int* __restrict__ row_ptr,
                                               const float* __restrict__ wbuf,
                                               float* __restrict__ out, int n, int ldo) {
  int node = blockIdx.x * 4 + (threadIdx.x >> 6);
  int lane = threadIdx.x & 63;
  if (node >= n) return;
  int beg = row_ptr[node], end = row_ptr[node + 1];
  float acc[KT];
#pragma unroll
  for (int k = 0; k < KT; ++k) acc[k] = 0.f;
  const float4* w4 = (const float4*)wbuf;
  int i = beg;
  for (; i + 4 <= end; i += 4) {
    float4 wa0 = w4[(size_t)(i + 0) * 2], wb0 = w4[(size_t)(i + 0) * 2 + 1];
    float4 wa1 = w4[(size_t)(i + 1) * 2], wb1 = w4[(size_t)(i + 1) * 2 + 1];
    float4 wa2 = w4[(size_t)(i + 2) * 2], wb2 = w4[(size_t)(i + 2) * 2 + 1];
    float4 wa3 = w4[(size_t)(i + 3) * 2], wb3 = w4[(size_t)(i + 3) * 2 + 1];
    int s0 = __float_as_int(wb0.z), s1 = __float_as_int(wb1.z);
    int s2 = __float_as_int(wb2.z), s3 = __float_as_int(wb3.z);
    float x0 = feat[(size_t)s0 * 64 + lane];
    float x1 = feat[(size_t)s1 * 64 + lane];
    float x2 = feat[(size_t)s2 * 64 + lane];
    float x3 = feat[(size_t)s3 * 64 + lane];
    agg_fma<KT>(acc, wa0, wb0, x0);
    agg_fma<KT>(acc, wa1, wb1, x1);
    agg_fma<KT>(acc, wa2, wb2, x2);
    agg_fma<KT>(acc, wa3, wb3, x3);
  }
  for (; i < end; ++i) {
    float4 wa = w4[(size_t)i * 2], wb = w4[(size_t)i * 2 + 1];
    int s = __float_as_int(wb.z);
    float xv = feat[(size_t)s * 64 + lane];
    agg_fma<KT>(acc, wa, wb, xv);
  }
  int degi = end - beg;
  float invdeg = 1.0f / (float)(degi > 1 ? degi : 1);
  size_t o = (size_t)node * ldo + lane;
#pragma unroll
  for (int k = 0; k < KT; ++k) out[o + k * 64] = acc[k] * invdeg;
}

// --- weight prep: Bout[(K*64+64) x 64] = [rearranged G ; root] ---------------
__global__ void prep_cat(const float* __restrict__ g, const float* __restrict__ root,
                         float* __restrict__ Bout, int K) {
  int idx = blockIdx.x * 256 + threadIdx.x;
  int total = (K + 1) * 64 * 64;
  if (idx >= total) return;
  int r = idx >> 6, c = idx & 63;
  float v;
  if (r < K * 64) {
    int k = r >> 6, i = r & 63;
    v = g[i * (K * 64) + k * 64 + c];
  } else {
    v = root[(r - K * 64) * 64 + c];
  }
  Bout[idx] = v;
}

// --- single GEMM: C = [A1(K1)|A2(64)]@B + bias ; fused BN stats -------------
__global__ __launch_bounds__(256) void gemm_fused(const float* __restrict__ A1, int lda1,
                                                  int K1, const float* __restrict__ A2,
                                                  const float* __restrict__ B,
                                                  const float* __restrict__ bias,
                                                  float* __restrict__ C, int M,
                                                  float* sums, float* sumsq) {
  __shared__ float As[64][68];
  __shared__ float Bs[64][64];
  __shared__ float red[16][64];
  int tile_m = blockIdx.x * 64;
  int tid = threadIdx.x, tx = tid & 15, ty = tid >> 4;
  float acc[4][4] = {};
  int nch = K1 >> 6;
  for (int ch = 0; ch <= nch; ++ch) {
    const float* Ap;
    int lda, kb;
    if (ch < nch) { Ap = A1; lda = lda1; kb = ch * 64; }
    else          { Ap = A2; lda = 64;   kb = 0; }
#pragma unroll
    for (int i = 0; i < 4; ++i) {
      int idx = tid + i * 256, r = idx >> 4, c4 = idx & 15;
      float4 v = make_float4(0.f, 0.f, 0.f, 0.f);
      if (tile_m + r < M) v = *(const float4*)&Ap[(size_t)(tile_m + r) * lda + kb + c4 * 4];
      *(float4*)&As[r][c4 * 4] = v;
      *(float4*)&Bs[r][c4 * 4] = *(const float4*)&B[(size_t)(ch * 64 + r) * 64 + c4 * 4];
    }
    __syncthreads();
#pragma unroll
    for (int k = 0; k < 64; k += 4) {
      float4 b0 = *(const float4*)&Bs[k + 0][tx * 4];
      float4 b1v = *(const float4*)&Bs[k + 1][tx * 4];
      float4 b2 = *(const float4*)&Bs[k + 2][tx * 4];
      float4 b3 = *(const float4*)&Bs[k + 3][tx * 4];
#pragma unroll
      for (int i = 0; i < 4; ++i) {
        float4 a = *(const float4*)&As[ty * 4 + i][k];
        acc[i][0] = fmaf(a.x, b0.x, acc[i][0]);
        acc[i][1] = fmaf(a.x, b0.y, acc[i][1]);
        acc[i][2] = fmaf(a.x, b0.z, acc[i][2]);
        acc[i][3] = fmaf(a.x, b0.w, acc[i][3]);
        acc[i][0] = fmaf(a.y, b1v.x, acc[i][0]);
        acc[i][1] = fmaf(a.y, b1v.y, acc[i][1]);
        acc[i][2] = fmaf(a.y, b1v.z, acc[i][2]);
        acc[i][3] = fmaf(a.y, b1v.w, acc[i][3]);
        acc[i][0] = fmaf(a.z, b2.x, acc[i][0]);
        acc[i][1] = fmaf(a.z, b2.y, acc[i][1]);
        acc[i][2] = fmaf(a.z, b2.z, acc[i][2]);
        acc[i][3] = fmaf(a.z, b2.w, acc[i][3]);
        acc[i][0] = fmaf(a.w, b3.x, acc[i][0]);
        acc[i][1] = fmaf(a.w, b3.y, acc[i][1]);
        acc[i][2] = fmaf(a.w, b3.z, acc[i][2]);
        acc[i][3] = fmaf(a.w, b3.w, acc[i][3]);
      }
    }
    __syncthreads();
  }
  float cs[4] = {}, cq[4] = {};
#pragma unroll
  for (int i = 0; i < 4; ++i) {
    int r = tile_m + ty * 4 + i;
    if (r < M) {
      int cc = tx * 4;
      float ov[4];
#pragma unroll
      for (int j = 0; j < 4; ++j) {
        ov[j] = acc[i][j] + bias[cc + j];
        cs[j] += ov[j];
        cq[j] = fmaf(ov[j], ov[j], cq[j]);
      }
      *(float4*)&C[(size_t)r * 64 + cc] = make_float4(ov[0], ov[1], ov[2], ov[3]);
    }
  }
#pragma unroll
  for (int j = 0; j < 4; ++j) red[ty][tx * 4 + j] = cs[j];
  __syncthreads();
  if (tid < 64) {
    float t = 0.f;
#pragma unroll
    for (int g = 0; g < 16; ++g) t += red[g][tid];
    atomicAdd(&sums[tid], t);
  }
  __syncthreads();
#pragma unroll
  for (int j = 0; j < 4; ++j) red[ty][tx * 4 + j] = cq[j];
  __syncthreads();
  if (tid < 64) {
    float t = 0.f;
#pragma unroll
    for (int g = 0; g < 16; ++g) t += red[g][tid];
    atomicAdd(&sumsq[tid], t);
  }
}

// --- batchnorm scale/shift + epilogues --------------------------------------
__global__ void bn_final(const float* sum, const float* sumsq, const float* gamma,
                         const float* beta, int n, float* scale, float* shift) {
  int c = threadIdx.x;
  float m = sum[c] / (float)n;
  float v = sumsq[c] / (float)n - m * m;
  float r = rsqrtf(v + BN_EPS);
  float s = r * gamma[c];
  scale[c] = s;
  shift[c] = beta[c] - m * s;
}

__global__ void norm_elu(float* h, const float* __restrict__ scale,
                         const float* __restrict__ shift, int total) {
  int i = blockIdx.x * 256 + threadIdx.x;
  if (i >= total) return;
  int c = i & 63;
  float v = h[i] * scale[c] + shift[c];
  h[i] = v > 0.f ? v : expm1f(v);
}

__global__ void final_kernel(const float* __restrict__ h2, const float* __restrict__ sc,
                             const float* __restrict__ s2, const float* __restrict__ t2,
                             const float* __restrict__ ss, const float* __restrict__ ts,
                             float* __restrict__ out, int total) {
  int i = blockIdx.x * 256 + threadIdx.x;
  if (i >= total) return;
  int c = i & 63;
  float v = h2[i] * s2[c] + t2[c] + sc[i] * ss[c] + ts[c];
  out[i] = v > 0.f ? v : expm1f(v);
}

// ---------------------------------------------------------------------------
extern "C" void kernel_launch(void* const* d_in, const int* in_sizes, int n_in,
                              void* d_out, int out_size, void* d_ws, size_t ws_size,
                              hipStream_t stream) {
  const float* x    = (const float*)d_in[0];
  const void*  ei   = d_in[1];
  const float* ea   = (const float*)d_in[2];
  const float* g1   = (const float*)d_in[3];
  const float* mu1  = (const float*)d_in[4];
  const float* sig1 = (const float*)d_in[5];
  const float* root1= (const float*)d_in[6];
  const float* b1   = (const float*)d_in[7];
  const float* gam1 = (const float*)d_in[8];
  const float* bet1 = (const float*)d_in[9];
  const float* g2   = (const float*)d_in[10];
  const float* mu2  = (const float*)d_in[11];
  const float* sig2 = (const float*)d_in[12];
  const float* root2= (const float*)d_in[13];
  const float* b2   = (const float*)d_in[14];
  const float* gam2 = (const float*)d_in[15];
  const float* bet2 = (const float*)d_in[16];
  const float* gs   = (const float*)d_in[17];
  const float* mus  = (const float*)d_in[18];
  const float* sigs = (const float*)d_in[19];
  const float* roots= (const float*)d_in[20];
  const float* bs   = (const float*)d_in[21];
  const float* gams = (const float*)d_in[22];
  const float* bets = (const float*)d_in[23];

  int N = in_sizes[0] / 64;
  int E = in_sizes[1] / 2;

  char* w = (char*)d_ws;
  auto alloc = [&](size_t bytes) {
    char* p = w;
    w += (bytes + 255) & ~(size_t)255;
    return p;
  };
  int*   flag    = (int*)alloc(256);
  int*   cnt     = (int*)alloc((size_t)N * 4);
  int*   row_ptr = (int*)alloc((size_t)(N + 1) * 4);
  int*   partials= (int*)alloc(256 * 4);
  int*   csr_src = (int*)alloc((size_t)E * 4);
  float* csr_ea  = (float*)alloc((size_t)E * 4);
  float* wbuf    = (float*)alloc((size_t)E * 8 * 4);    // [E][8] records {w0..w5,src,0}
  float* Abuf    = (float*)alloc((size_t)N * 384 * 4);  // agg outputs
  float* h       = (float*)alloc((size_t)N * 64 * 4);
  float* h2      = (float*)alloc((size_t)N * 64 * 4);
  float* scb     = (float*)alloc((size_t)N * 64 * 4);
  float* B1cat   = (float*)alloc(384 * 64 * 4);
  float* B2cat   = (float*)alloc(384 * 64 * 4);
  float* Bsc     = (float*)alloc(128 * 64 * 4);
  float* stats   = (float*)alloc(12 * 64 * 4);

  hipMemsetAsync(cnt, 0, (size_t)N * 4, stream);
  hipMemsetAsync(stats, 0, 12 * 64 * 4, stream);

  int eb = (E + 255) / 256;
  int nb1 = (N + 2047) / 2048;

  prep_cat<<<(6 * 4096 + 255) / 256, 256, 0, stream>>>(g1, root1, B1cat, 5);
  prep_cat<<<(6 * 4096 + 255) / 256, 256, 0, stream>>>(g2, root2, B2cat, 5);
  prep_cat<<<(2 * 4096 + 255) / 256, 256, 0, stream>>>(gs, roots, Bsc, 1);

  detect_kernel<<<1, 1, 0, stream>>>(ei, flag);
  hist_kernel<<<eb, 256, 0, stream>>>(ei, E, flag, cnt);
  scan1<<<nb1, 256, 0, stream>>>(cnt, row_ptr, partials, N);
  scan2<<<1, 256, 0, stream>>>(partials, nb1, row_ptr, N);
  scan3<<<(N + 255) / 256, 256, 0, stream>>>(row_ptr, partials, cnt, N);
  scatter_kernel<<<eb, 256, 0, stream>>>(ei, ea, E, flag, row_ptr, cnt, csr_src, csr_ea);

  int mtiles = (N + 63) / 64;
  int nb_node = (N + 3) / 4;
  int nb_elem = (N * 64 + 255) / 256;

  // ---- layer1 + shortcut ----
  wgt_kernel<5, 1><<<eb, 256, 0, stream>>>(csr_ea, csr_src, E, mu1, sig1, mus, sigs, wbuf);
  agg_pre<6><<<nb_node, 256, 0, stream>>>(x, row_ptr, wbuf, Abuf, N, 384);
  // h = [agg1 | x] @ [G1r; root1] + b1   (+BN1 stats)
  gemm_fused<<<mtiles, 256, 0, stream>>>(Abuf, 384, 320, x, B1cat, b1, h, N,
                                         stats + 0 * 64, stats + 1 * 64);
  // scb = [aggsc | x] @ [gs; roots] + bs (+BNsc stats)
  gemm_fused<<<mtiles, 256, 0, stream>>>(Abuf + 320, 384, 64, x, Bsc, bs, scb, N,
                                         stats + 4 * 64, stats + 5 * 64);
  bn_final<<<1, 64, 0, stream>>>(stats + 0 * 64, stats + 1 * 64, gam1, bet1, N,
                                 stats + 6 * 64, stats + 7 * 64);
  norm_elu<<<nb_elem, 256, 0, stream>>>(h, stats + 6 * 64, stats + 7 * 64, N * 64);

  // ---- layer2 ----
  wgt_kernel<5, 0><<<eb, 256, 0, stream>>>(csr_ea, csr_src, E, mu2, sig2, nullptr, nullptr, wbuf);
  agg_pre<5><<<nb_node, 256, 0, stream>>>(h, row_ptr, wbuf, Abuf, N, 320);
  gemm_fused<<<mtiles, 256, 0, stream>>>(Abuf, 320, 320, h, B2cat, b2, h2, N,
                                         stats + 2 * 64, stats + 3 * 64);

  bn_final<<<1, 64, 0, stream>>>(stats + 2 * 64, stats + 3 * 64, gam2, bet2, N,
                                 stats + 8 * 64, stats + 9 * 64);
  bn_final<<<1, 64, 0, stream>>>(stats + 4 * 64, stats + 5 * 64, gams, bets, N,
                                 stats + 10 * 64, stats + 11 * 64);

  final_kernel<<<nb_elem, 256, 0, stream>>>(h2, scb, stats + 8 * 64, stats + 9 * 64,
                                            stats + 10 * 64, stats + 11 * 64,
                                            (float*)d_out, N * 64);
}